// Round 1
// baseline (104.317 us; speedup 1.0000x reference)
//
#include <hip/hip_runtime.h>

#define BATCH 4
#define NPTS 8192
#define PTOT (BATCH * NPTS)        // 32768 points per cloud
#define NSPLIT 4
#define SPLIT_LEN (NPTS / NSPLIT)  // 2048

// ---------------------------------------------------------------------------
// ws layout (float4-aligned):
//   packed  : [2*PTOT] float4   -- pred points then target points, (-2x,-2y,-2z,|r|^2)
//   partial : [2*PTOT] float4   -- per point, per split partial min of s
//   blockSums : [256] float
// total ~2.1 MB
// ---------------------------------------------------------------------------

__global__ __launch_bounds__(256) void pack_k(const float* __restrict__ pred,
                                              const float* __restrict__ tgt,
                                              float4* __restrict__ packed) {
    int i = blockIdx.x * 256 + threadIdx.x;
    if (i >= 2 * PTOT) return;
    const float* src = (i < PTOT) ? pred : tgt;
    int j = (i < PTOT) ? i : i - PTOT;
    float x = src[3 * j + 0];
    float y = src[3 * j + 1];
    float z = src[3 * j + 2];
    packed[i] = make_float4(-2.0f * x, -2.0f * y, -2.0f * z, x * x + y * y + z * z);
}

__device__ __forceinline__ float dot_s(const float4 r, float px, float py, float pz) {
    // s = |r|^2 - 2*(rx*px + ry*py + rz*pz), with (-2rx,-2ry,-2rz,|r|^2) packed
    return fmaf(r.x, px, fmaf(r.y, py, fmaf(r.z, pz, r.w)));
}

__global__ __launch_bounds__(256) void chamfer_min_k(const float* __restrict__ pred,
                                                     const float* __restrict__ tgt,
                                                     const float4* __restrict__ packed,
                                                     float* __restrict__ partial) {
    int bid   = blockIdx.x;
    int split = bid & (NSPLIT - 1);
    int chunk = (bid >> 2) & 31;   // NPTS/256 = 32 chunks
    int b     = (bid >> 7) & 3;
    int dir   = bid >> 9;          // 0: pred->target, 1: target->pred

    int p = chunk * 256 + threadIdx.x;

    const float* pp = (dir ? tgt : pred) + (b * NPTS + p) * 3;
    float px = pp[0], py = pp[1], pz = pp[2];

    // refs: the *other* cloud's packed array for this batch
    const float4* rf = packed + (dir ? 0 : PTOT) + b * NPTS;

    int base = split * SPLIT_LEN;
    float a0 = 1e30f, a1 = 1e30f, a2 = 1e30f, a3 = 1e30f;

    for (int m = base; m < base + SPLIT_LEN; m += 8) {
        float4 r0 = rf[m + 0];
        float4 r1 = rf[m + 1];
        float4 r2 = rf[m + 2];
        float4 r3 = rf[m + 3];
        float4 r4 = rf[m + 4];
        float4 r5 = rf[m + 5];
        float4 r6 = rf[m + 6];
        float4 r7 = rf[m + 7];
        a0 = fminf(a0, dot_s(r0, px, py, pz));
        a1 = fminf(a1, dot_s(r1, px, py, pz));
        a2 = fminf(a2, dot_s(r2, px, py, pz));
        a3 = fminf(a3, dot_s(r3, px, py, pz));
        a0 = fminf(a0, dot_s(r4, px, py, pz));
        a1 = fminf(a1, dot_s(r5, px, py, pz));
        a2 = fminf(a2, dot_s(r6, px, py, pz));
        a3 = fminf(a3, dot_s(r7, px, py, pz));
    }

    float s = fminf(fminf(a0, a1), fminf(a2, a3));
    partial[((dir * BATCH + b) * NPTS + p) * NSPLIT + split] = s;
}

__global__ __launch_bounds__(256) void combine_k(const float4* __restrict__ packed,
                                                 const float4* __restrict__ partial4,
                                                 float* __restrict__ blockSums) {
    int q = blockIdx.x * 256 + threadIdx.x;   // global point index, [0, 2*PTOT)
    float4 v = partial4[q];
    float s = fminf(fminf(v.x, v.y), fminf(v.z, v.w));
    float val = fmaxf(packed[q].w + s, 0.0f);  // add |p|^2, clamp

    // deterministic block reduction: wave shfl tree + LDS across 4 waves
    for (int off = 32; off > 0; off >>= 1)
        val += __shfl_down(val, off, 64);
    __shared__ float lds[4];
    int lane = threadIdx.x & 63;
    int w    = threadIdx.x >> 6;
    if (lane == 0) lds[w] = val;
    __syncthreads();
    if (threadIdx.x == 0)
        blockSums[blockIdx.x] = (lds[0] + lds[1]) + (lds[2] + lds[3]);
}

__global__ __launch_bounds__(256) void final_k(const float* __restrict__ blockSums,
                                               float* __restrict__ out) {
    float v = blockSums[threadIdx.x];  // exactly 256 block sums
    for (int off = 32; off > 0; off >>= 1)
        v += __shfl_down(v, off, 64);
    __shared__ float lds[4];
    int lane = threadIdx.x & 63;
    int w    = threadIdx.x >> 6;
    if (lane == 0) lds[w] = v;
    __syncthreads();
    if (threadIdx.x == 0)
        out[0] = ((lds[0] + lds[1]) + (lds[2] + lds[3])) * (1.0f / 32768.0f);
}

extern "C" void kernel_launch(void* const* d_in, const int* in_sizes, int n_in,
                              void* d_out, int out_size, void* d_ws, size_t ws_size,
                              hipStream_t stream) {
    const float* pred = (const float*)d_in[0];
    const float* tgt  = (const float*)d_in[1];

    float4* packed    = (float4*)d_ws;
    float*  partial   = (float*)(packed + 2 * PTOT);
    float*  blockSums = partial + 2 * PTOT * 4;

    pack_k<<<(2 * PTOT + 255) / 256, 256, 0, stream>>>(pred, tgt, packed);
    chamfer_min_k<<<2 * BATCH * (NPTS / 256) * NSPLIT, 256, 0, stream>>>(pred, tgt, packed, partial);
    combine_k<<<(2 * PTOT) / 256, 256, 0, stream>>>(packed, (const float4*)partial, blockSums);
    final_k<<<1, 256, 0, stream>>>(blockSums, (float*)d_out);
}

// Round 2
// 66.841 us; speedup vs baseline: 1.5607x; 1.5607x over previous
//
#include <hip/hip_runtime.h>

#define BATCH 4
#define NPTS 8192
#define PTOT (BATCH * NPTS)   // 32768 points per cloud

typedef __attribute__((ext_vector_type(8))) short short8;     // 8 bf16 = 4 VGPRs
typedef __attribute__((ext_vector_type(16))) float f32x16;    // MFMA 32x32 accumulator

__device__ __forceinline__ ushort f2bf(float f) {             // RNE float->bf16 bits
    unsigned u = __float_as_uint(f);
    unsigned r = (u + 0x7fffu + ((u >> 16) & 1u)) >> 16;
    return (ushort)r;
}
__device__ __forceinline__ float bf2f(ushort b) {
    return __uint_as_float(((unsigned)b) << 16);
}

// ---------------------------------------------------------------------------
// Panels: [cloud][PTOT][16] bf16.  For point p with coords c, n2 = |c|^2:
//   A row: [ch0,ch1,ch2, cl0,cl1,cl2, ch0,ch1,ch2, cl0,cl1,cl2, n2h, n2l, 1, 1]
//   B row: [-2ch0..2, -2ch0..2, -2cl0..2, -2cl0..2, 1, 1, n2h, n2l]
// A_n . B_m = -2*(xh+xl).(yh+yl) + x2h+x2l + y2h+y2l  ~= ||x-y||^2  (exact
// products; only the hi/lo split residual ~2^-17 remains)
// ---------------------------------------------------------------------------
__global__ __launch_bounds__(256) void pack_k(const float* __restrict__ pred,
                                              const float* __restrict__ tgt,
                                              ushort* __restrict__ Apan,
                                              ushort* __restrict__ Bpan) {
    int i = blockIdx.x * 256 + threadIdx.x;      // [0, 2*PTOT), cloud-major
    int cloud = (i >= PTOT) ? 1 : 0;
    int j = cloud ? i - PTOT : i;
    const float* s = cloud ? tgt : pred;
    float c0 = s[3 * j + 0], c1 = s[3 * j + 1], c2 = s[3 * j + 2];
    float c[3] = {c0, c1, c2};
    ushort hh[3], ll[3], mh[3], ml[3];
#pragma unroll
    for (int d = 0; d < 3; ++d) {
        ushort h = f2bf(c[d]); float hf = bf2f(h);
        ushort l = f2bf(c[d] - hf); float lf = bf2f(l);   // exact residual split
        hh[d] = h; ll[d] = l;
        mh[d] = f2bf(-2.0f * hf);                         // exact (pow2 scale)
        ml[d] = f2bf(-2.0f * lf);
    }
    float n2 = fmaf(c0, c0, fmaf(c1, c1, c2 * c2));
    ushort n2h = f2bf(n2);
    ushort n2l = f2bf(n2 - bf2f(n2h));
    const ushort ONE = 0x3F80;

    __attribute__((aligned(16))) ushort a[16] = {
        hh[0], hh[1], hh[2], ll[0], ll[1], ll[2],
        hh[0], hh[1], hh[2], ll[0], ll[1], ll[2],
        n2h, n2l, ONE, ONE};
    __attribute__((aligned(16))) ushort b[16] = {
        mh[0], mh[1], mh[2], mh[0], mh[1], mh[2],
        ml[0], ml[1], ml[2], ml[0], ml[1], ml[2],
        ONE, ONE, n2h, n2l};

    ushort* ad = Apan + (size_t)i * 16;
    ushort* bd = Bpan + (size_t)i * 16;
    *(uint4*)ad       = *(const uint4*)a;
    *(uint4*)(ad + 8) = *(const uint4*)(a + 8);
    *(uint4*)bd       = *(const uint4*)b;
    *(uint4*)(bd + 8) = *(const uint4*)(b + 8);
}

// ---------------------------------------------------------------------------
// Grid: 1024 blocks = jhalf(2) x dir(2) x batch(4) x strip(64).
// Block: 4 waves, each owns one 32-row tile of its 128-row strip; iterates 128
// column tiles (half of 8192/32) with mfma_f32_32x32x16_bf16 (K=16 exact),
// keeping 16 running mins in registers. Cross-lane min once at the end.
// part layout: [jhalf][dir][batch][NPTS].
// ---------------------------------------------------------------------------
__global__ __launch_bounds__(256) void chamfer_mfma_k(const ushort* __restrict__ Apan,
                                                      const ushort* __restrict__ Bpan,
                                                      float* __restrict__ part) {
    int bid   = blockIdx.x;
    int strip = bid & 63;
    int b     = (bid >> 6) & 3;
    int dir   = (bid >> 8) & 1;
    int jh    = bid >> 9;
    int lane  = threadIdx.x & 63;
    int wave  = threadIdx.x >> 6;

    const ushort* Ap = Apan + ((size_t)dir * PTOT + (size_t)b * NPTS) * 16;
    const ushort* Bp = Bpan + ((size_t)(1 - dir) * PTOT + (size_t)b * NPTS) * 16;

    int rowbase = strip * 128 + wave * 32;
    // A frag: row = lane&31, k = 8*(lane>>5)+0..7  -> one 16B load, reused 128x
    const short8 af = *reinterpret_cast<const short8*>(
        Ap + (size_t)(rowbase + (lane & 31)) * 16 + 8 * (lane >> 5));

    // B frag base: col = lane&31, k = 8*(lane>>5); tile stride = 32*16 ushorts
    const ushort* bptr = Bp + (size_t)(lane & 31) * 16 + 8 * (lane >> 5)
                            + (size_t)jh * 128 * 512;

    f32x16 zero = {};
    float run[16];
#pragma unroll
    for (int r = 0; r < 16; ++r) run[r] = 1e30f;

    for (int j = 0; j < 128; j += 2) {
        short8 b0 = *reinterpret_cast<const short8*>(bptr + (size_t)j * 512);
        short8 b1 = *reinterpret_cast<const short8*>(bptr + (size_t)j * 512 + 512);
        f32x16 acc0 = __builtin_amdgcn_mfma_f32_32x32x16_bf16(af, b0, zero, 0, 0, 0);
        f32x16 acc1 = __builtin_amdgcn_mfma_f32_32x32x16_bf16(af, b1, zero, 0, 0, 0);
#pragma unroll
        for (int r = 0; r < 16; ++r) run[r] = fminf(run[r], acc0[r]);
#pragma unroll
        for (int r = 0; r < 16; ++r) run[r] = fminf(run[r], acc1[r]);
    }

    // C/D layout (verified m74/m101): col = lane&31, row = (r&3)+8*(r>>2)+4*(lane>>5)
#pragma unroll
    for (int r = 0; r < 16; ++r) {
        float v = run[r];
        v = fminf(v, __shfl_xor(v, 1, 32));
        v = fminf(v, __shfl_xor(v, 2, 32));
        v = fminf(v, __shfl_xor(v, 4, 32));
        v = fminf(v, __shfl_xor(v, 8, 32));
        v = fminf(v, __shfl_xor(v, 16, 32));
        if ((lane & 31) == 0) {
            int row = (r & 3) + 8 * (r >> 2) + 4 * (lane >> 5);
            part[(((size_t)jh * 2 + dir) * BATCH + b) * NPTS + rowbase + row] = v;
        }
    }
}

// Combine jhalves (min), clamp, deterministic sum, scale.
__global__ __launch_bounds__(1024) void reduce_k(const float* __restrict__ part,
                                                 float* __restrict__ out) {
    int t = threadIdx.x;
    float s = 0.0f;
    for (int i = 0; i < 64; ++i) {
        int idx = t + i * 1024;                         // [0, 65536)
        float v = fmaxf(fminf(part[idx], part[idx + 65536]), 0.0f);
        s += v;
    }
    for (int off = 32; off; off >>= 1) s += __shfl_down(s, off, 64);
    __shared__ float lds[16];
    if ((t & 63) == 0) lds[t >> 6] = s;
    __syncthreads();
    if (t == 0) {
        float tot = 0.0f;
#pragma unroll
        for (int w = 0; w < 16; ++w) tot += lds[w];
        out[0] = tot * (1.0f / 32768.0f);
    }
}

extern "C" void kernel_launch(void* const* d_in, const int* in_sizes, int n_in,
                              void* d_out, int out_size, void* d_ws, size_t ws_size,
                              hipStream_t stream) {
    const float* pred = (const float*)d_in[0];
    const float* tgt  = (const float*)d_in[1];

    ushort* Apan = (ushort*)d_ws;                        // 2*PTOT*16 bf16 = 2 MB
    ushort* Bpan = Apan + (size_t)2 * PTOT * 16;         // 2 MB
    float*  part = (float*)(Bpan + (size_t)2 * PTOT * 16); // 131072 floats = 512 KB

    pack_k<<<(2 * PTOT) / 256, 256, 0, stream>>>(pred, tgt, Apan, Bpan);
    chamfer_mfma_k<<<1024, 256, 0, stream>>>(Apan, Bpan, part);
    reduce_k<<<1, 1024, 0, stream>>>(part, (float*)d_out);
}

// Round 3
// 52.830 us; speedup vs baseline: 1.9746x; 1.2652x over previous
//
#include <hip/hip_runtime.h>

#define BATCH 4
#define NPTS 8192
#define PTOT (BATCH * NPTS)   // 32768 points per cloud
#define NJH 4                 // column-range splits
#define TILES_PER_WAVE (NPTS / 32 / NJH)   // 64

typedef __attribute__((ext_vector_type(8))) short short8;     // 8 bf16 = 4 VGPRs
typedef __attribute__((ext_vector_type(16))) float f32x16;    // MFMA 32x32 accumulator

__device__ __forceinline__ ushort f2bf(float f) {             // RNE float->bf16 bits
    unsigned u = __float_as_uint(f);
    unsigned r = (u + 0x7fffu + ((u >> 16) & 1u)) >> 16;
    return (ushort)r;
}
__device__ __forceinline__ float bf2f(ushort b) {
    return __uint_as_float(((unsigned)b) << 16);
}

// ---------------------------------------------------------------------------
// Panels: [cloud][PTOT][16] bf16.  For point p with coords c, n2 = |c|^2:
//   A row: [ch0,ch1,ch2, cl0,cl1,cl2, ch0,ch1,ch2, cl0,cl1,cl2, n2h, n2l, 1, 1]
//   B row: [-2ch0..2, -2ch0..2, -2cl0..2, -2cl0..2, 1, 1, n2h, n2l]
// A_n . B_m = -2*(xh+xl).(yh+yl) + x2h+x2l + y2h+y2l  ~= ||x-y||^2
// ---------------------------------------------------------------------------
__global__ __launch_bounds__(256) void pack_k(const float* __restrict__ pred,
                                              const float* __restrict__ tgt,
                                              ushort* __restrict__ Apan,
                                              ushort* __restrict__ Bpan) {
    int i = blockIdx.x * 256 + threadIdx.x;      // [0, 2*PTOT), cloud-major
    int cloud = (i >= PTOT) ? 1 : 0;
    int j = cloud ? i - PTOT : i;
    const float* s = cloud ? tgt : pred;
    float c0 = s[3 * j + 0], c1 = s[3 * j + 1], c2 = s[3 * j + 2];
    float c[3] = {c0, c1, c2};
    ushort hh[3], ll[3], mh[3], ml[3];
#pragma unroll
    for (int d = 0; d < 3; ++d) {
        ushort h = f2bf(c[d]); float hf = bf2f(h);
        ushort l = f2bf(c[d] - hf); float lf = bf2f(l);   // exact residual split
        hh[d] = h; ll[d] = l;
        mh[d] = f2bf(-2.0f * hf);                         // exact (pow2 scale)
        ml[d] = f2bf(-2.0f * lf);
    }
    float n2 = fmaf(c0, c0, fmaf(c1, c1, c2 * c2));
    ushort n2h = f2bf(n2);
    ushort n2l = f2bf(n2 - bf2f(n2h));
    const ushort ONE = 0x3F80;

    __attribute__((aligned(16))) ushort a[16] = {
        hh[0], hh[1], hh[2], ll[0], ll[1], ll[2],
        hh[0], hh[1], hh[2], ll[0], ll[1], ll[2],
        n2h, n2l, ONE, ONE};
    __attribute__((aligned(16))) ushort b[16] = {
        mh[0], mh[1], mh[2], mh[0], mh[1], mh[2],
        ml[0], ml[1], ml[2], ml[0], ml[1], ml[2],
        ONE, ONE, n2h, n2l};

    ushort* ad = Apan + (size_t)i * 16;
    ushort* bd = Bpan + (size_t)i * 16;
    *(uint4*)ad       = *(const uint4*)a;
    *(uint4*)(ad + 8) = *(const uint4*)(a + 8);
    *(uint4*)bd       = *(const uint4*)b;
    *(uint4*)(bd + 8) = *(const uint4*)(b + 8);
}

// ---------------------------------------------------------------------------
// Grid: 2048 blocks = jh(4) x dir(2) x batch(4) x strip(64).
// Block: 4 waves, each owns one 32-row tile of its 128-row strip; iterates 64
// column tiles with mfma_f32_32x32x16_bf16 (K=16 exact), v_min3 epilogue into
// 16 running mins, software-pipelined B-frag loads.
// part layout: [jh][dir][batch][NPTS].
// ---------------------------------------------------------------------------
__global__ __launch_bounds__(256) void chamfer_mfma_k(const ushort* __restrict__ Apan,
                                                      const ushort* __restrict__ Bpan,
                                                      float* __restrict__ part) {
    int bid   = blockIdx.x;
    int strip = bid & 63;
    int b     = (bid >> 6) & 3;
    int dir   = (bid >> 8) & 1;
    int jh    = bid >> 9;          // 0..3
    int lane  = threadIdx.x & 63;
    int wave  = threadIdx.x >> 6;

    const ushort* Ap = Apan + ((size_t)dir * PTOT + (size_t)b * NPTS) * 16;
    const ushort* Bp = Bpan + ((size_t)(1 - dir) * PTOT + (size_t)b * NPTS) * 16;

    int rowbase = strip * 128 + wave * 32;
    // A frag: row = lane&31, k = 8*(lane>>5)+0..7  -> one 16B load, reused 64x
    const short8 af = *reinterpret_cast<const short8*>(
        Ap + (size_t)(rowbase + (lane & 31)) * 16 + 8 * (lane >> 5));

    // B frag base: col = lane&31, k = 8*(lane>>5); tile stride = 32*16 ushorts
    const ushort* bptr = Bp + (size_t)(lane & 31) * 16 + 8 * (lane >> 5)
                            + (size_t)jh * TILES_PER_WAVE * 512;

    f32x16 zero = {};
    float run[16];
#pragma unroll
    for (int r = 0; r < 16; ++r) run[r] = 1e30f;

    // software pipeline: keep next pair of B-frags in flight over MFMA+min
    short8 c0 = *reinterpret_cast<const short8*>(bptr);
    short8 c1 = *reinterpret_cast<const short8*>(bptr + 512);
    for (int j = 2; j < TILES_PER_WAVE; j += 2) {
        short8 n0 = *reinterpret_cast<const short8*>(bptr + (size_t)j * 512);
        short8 n1 = *reinterpret_cast<const short8*>(bptr + (size_t)j * 512 + 512);
        f32x16 acc0 = __builtin_amdgcn_mfma_f32_32x32x16_bf16(af, c0, zero, 0, 0, 0);
        f32x16 acc1 = __builtin_amdgcn_mfma_f32_32x32x16_bf16(af, c1, zero, 0, 0, 0);
#pragma unroll
        for (int r = 0; r < 16; ++r)
            run[r] = fminf(run[r], fminf(acc0[r], acc1[r]));   // -> v_min3_f32
        c0 = n0; c1 = n1;
    }
    {
        f32x16 acc0 = __builtin_amdgcn_mfma_f32_32x32x16_bf16(af, c0, zero, 0, 0, 0);
        f32x16 acc1 = __builtin_amdgcn_mfma_f32_32x32x16_bf16(af, c1, zero, 0, 0, 0);
#pragma unroll
        for (int r = 0; r < 16; ++r)
            run[r] = fminf(run[r], fminf(acc0[r], acc1[r]));
    }

    // C/D layout (verified): col = lane&31, row = (r&3)+8*(r>>2)+4*(lane>>5)
#pragma unroll
    for (int r = 0; r < 16; ++r) {
        float v = run[r];
        v = fminf(v, __shfl_xor(v, 1, 32));
        v = fminf(v, __shfl_xor(v, 2, 32));
        v = fminf(v, __shfl_xor(v, 4, 32));
        v = fminf(v, __shfl_xor(v, 8, 32));
        v = fminf(v, __shfl_xor(v, 16, 32));
        if ((lane & 31) == 0) {
            int row = (r & 3) + 8 * (r >> 2) + 4 * (lane >> 5);
            part[(((size_t)jh * 2 + dir) * BATCH + b) * NPTS + rowbase + row] = v;
        }
    }
}

// Combine jh splits (min of 4), clamp, deterministic sum, scale.
__global__ __launch_bounds__(1024) void reduce_k(const float* __restrict__ part,
                                                 float* __restrict__ out) {
    int t = threadIdx.x;
    float s = 0.0f;
    for (int i = 0; i < 64; ++i) {
        int idx = t + i * 1024;                         // [0, 65536)
        float v0 = fminf(part[idx],           part[idx + 1 * 65536]);
        float v1 = fminf(part[idx + 2 * 65536], part[idx + 3 * 65536]);
        s += fmaxf(fminf(v0, v1), 0.0f);
    }
    for (int off = 32; off; off >>= 1) s += __shfl_down(s, off, 64);
    __shared__ float lds[16];
    if ((t & 63) == 0) lds[t >> 6] = s;
    __syncthreads();
    if (t == 0) {
        float tot = 0.0f;
#pragma unroll
        for (int w = 0; w < 16; ++w) tot += lds[w];
        out[0] = tot * (1.0f / 32768.0f);
    }
}

extern "C" void kernel_launch(void* const* d_in, const int* in_sizes, int n_in,
                              void* d_out, int out_size, void* d_ws, size_t ws_size,
                              hipStream_t stream) {
    const float* pred = (const float*)d_in[0];
    const float* tgt  = (const float*)d_in[1];

    ushort* Apan = (ushort*)d_ws;                          // 2 MB
    ushort* Bpan = Apan + (size_t)2 * PTOT * 16;           // 2 MB
    float*  part = (float*)(Bpan + (size_t)2 * PTOT * 16); // NJH*2*PTOT floats = 1 MB

    pack_k<<<(2 * PTOT) / 256, 256, 0, stream>>>(pred, tgt, Apan, Bpan);
    chamfer_mfma_k<<<NJH * 2 * BATCH * 64, 256, 0, stream>>>(Apan, Bpan, part);
    reduce_k<<<1, 1024, 0, stream>>>(part, (float*)d_out);
}

// Round 4
// 45.743 us; speedup vs baseline: 2.2805x; 1.1549x over previous
//
#include <hip/hip_runtime.h>

#define BATCH 4
#define NPTS 8192
#define PTOT (BATCH * NPTS)   // 32768 points per cloud
#define NJH 8                 // column-range splits
#define TILES (NPTS / 32 / NJH)   // 32 col-tiles per jh range

typedef __attribute__((ext_vector_type(8))) short short8;     // 8 bf16 = 4 VGPRs
typedef __attribute__((ext_vector_type(16))) float f32x16;    // MFMA 32x32 accumulator

__device__ __forceinline__ ushort f2bf(float f) {             // RNE float->bf16 bits
    unsigned u = __float_as_uint(f);
    unsigned r = (u + 0x7fffu + ((u >> 16) & 1u)) >> 16;
    return (ushort)r;
}
__device__ __forceinline__ float bf2f(ushort b) {
    return __uint_as_float(((unsigned)b) << 16);
}

// ---------------------------------------------------------------------------
// Panels: [cloud][PTOT][16] bf16.  For point p with coords c, n2 = |c|^2:
//   A row: [ch0,ch1,ch2, cl0,cl1,cl2, ch0,ch1,ch2, cl0,cl1,cl2, n2h, n2l, 1, 1]
//   B row: [-2ch0..2, -2ch0..2, -2cl0..2, -2cl0..2, 1, 1, n2h, n2l]
// A_n . B_m = -2*(xh+xl).(yh+yl) + x2h+x2l + y2h+y2l  ~= ||x-y||^2
// ---------------------------------------------------------------------------
__global__ __launch_bounds__(256) void pack_k(const float* __restrict__ pred,
                                              const float* __restrict__ tgt,
                                              ushort* __restrict__ Apan,
                                              ushort* __restrict__ Bpan) {
    int i = blockIdx.x * 256 + threadIdx.x;      // [0, 2*PTOT), cloud-major
    int cloud = (i >= PTOT) ? 1 : 0;
    int j = cloud ? i - PTOT : i;
    const float* s = cloud ? tgt : pred;
    float c0 = s[3 * j + 0], c1 = s[3 * j + 1], c2 = s[3 * j + 2];
    float c[3] = {c0, c1, c2};
    ushort hh[3], ll[3], mh[3], ml[3];
#pragma unroll
    for (int d = 0; d < 3; ++d) {
        ushort h = f2bf(c[d]); float hf = bf2f(h);
        ushort l = f2bf(c[d] - hf); float lf = bf2f(l);   // exact residual split
        hh[d] = h; ll[d] = l;
        mh[d] = f2bf(-2.0f * hf);                         // exact (pow2 scale)
        ml[d] = f2bf(-2.0f * lf);
    }
    float n2 = fmaf(c0, c0, fmaf(c1, c1, c2 * c2));
    ushort n2h = f2bf(n2);
    ushort n2l = f2bf(n2 - bf2f(n2h));
    const ushort ONE = 0x3F80;

    __attribute__((aligned(16))) ushort a[16] = {
        hh[0], hh[1], hh[2], ll[0], ll[1], ll[2],
        hh[0], hh[1], hh[2], ll[0], ll[1], ll[2],
        n2h, n2l, ONE, ONE};
    __attribute__((aligned(16))) ushort b[16] = {
        mh[0], mh[1], mh[2], mh[0], mh[1], mh[2],
        ml[0], ml[1], ml[2], ml[0], ml[1], ml[2],
        ONE, ONE, n2h, n2l};

    ushort* ad = Apan + (size_t)i * 16;
    ushort* bd = Bpan + (size_t)i * 16;
    *(uint4*)ad       = *(const uint4*)a;
    *(uint4*)(ad + 8) = *(const uint4*)(a + 8);
    *(uint4*)bd       = *(const uint4*)b;
    *(uint4*)(bd + 8) = *(const uint4*)(b + 8);
}

// ---------------------------------------------------------------------------
// Grid: 2048 blocks = jh(8) x dir(2) x batch(4) x strip(32).
// Block: 4 waves; each wave owns TWO 32-row tiles (64 rows) of its 256-row
// strip; iterates 32 col-tiles with mfma_f32_32x32x16_bf16. Each B-frag pair
// feeds 4 MFMAs (2 row-tiles), min3 epilogue (8 min3/MFMA, optimal), 1-deep
// software pipeline on B loads.  part layout: [jh][dir][batch][NPTS].
// ---------------------------------------------------------------------------
__global__ __launch_bounds__(256) void chamfer_mfma_k(const ushort* __restrict__ Apan,
                                                      const ushort* __restrict__ Bpan,
                                                      float* __restrict__ part) {
    int bid   = blockIdx.x;
    int strip = bid & 31;
    int b     = (bid >> 5) & 3;
    int dir   = (bid >> 7) & 1;
    int jh    = bid >> 8;          // 0..7
    int lane  = threadIdx.x & 63;
    int wave  = threadIdx.x >> 6;

    const ushort* Ap = Apan + ((size_t)dir * PTOT + (size_t)b * NPTS) * 16;
    const ushort* Bp = Bpan + ((size_t)(1 - dir) * PTOT + (size_t)b * NPTS) * 16;

    int rowbase = strip * 256 + wave * 64;
    // A frags: row = lane&31 (+32 for 2nd tile), k = 8*(lane>>5)+0..7
    const short8 af0 = *reinterpret_cast<const short8*>(
        Ap + (size_t)(rowbase + (lane & 31)) * 16 + 8 * (lane >> 5));
    const short8 af1 = *reinterpret_cast<const short8*>(
        Ap + (size_t)(rowbase + 32 + (lane & 31)) * 16 + 8 * (lane >> 5));

    // B frag base: col = lane&31, k = 8*(lane>>5); tile stride = 512 ushorts
    const ushort* bptr = Bp + (size_t)(lane & 31) * 16 + 8 * (lane >> 5)
                            + (size_t)jh * TILES * 512;

    f32x16 zero = {};
    float run0[16], run1[16];
#pragma unroll
    for (int r = 0; r < 16; ++r) { run0[r] = 1e30f; run1[r] = 1e30f; }

    // software pipeline: next pair of B-frags in flight over 4 MFMA + 32 min3
    short8 c0 = *reinterpret_cast<const short8*>(bptr);
    short8 c1 = *reinterpret_cast<const short8*>(bptr + 512);
    for (int j = 2; j < TILES; j += 2) {
        short8 n0 = *reinterpret_cast<const short8*>(bptr + (size_t)j * 512);
        short8 n1 = *reinterpret_cast<const short8*>(bptr + (size_t)j * 512 + 512);
        f32x16 a00 = __builtin_amdgcn_mfma_f32_32x32x16_bf16(af0, c0, zero, 0, 0, 0);
        f32x16 a01 = __builtin_amdgcn_mfma_f32_32x32x16_bf16(af0, c1, zero, 0, 0, 0);
#pragma unroll
        for (int r = 0; r < 16; ++r)
            run0[r] = fminf(run0[r], fminf(a00[r], a01[r]));   // v_min3_f32
        f32x16 a10 = __builtin_amdgcn_mfma_f32_32x32x16_bf16(af1, c0, zero, 0, 0, 0);
        f32x16 a11 = __builtin_amdgcn_mfma_f32_32x32x16_bf16(af1, c1, zero, 0, 0, 0);
#pragma unroll
        for (int r = 0; r < 16; ++r)
            run1[r] = fminf(run1[r], fminf(a10[r], a11[r]));
        c0 = n0; c1 = n1;
    }
    {
        f32x16 a00 = __builtin_amdgcn_mfma_f32_32x32x16_bf16(af0, c0, zero, 0, 0, 0);
        f32x16 a01 = __builtin_amdgcn_mfma_f32_32x32x16_bf16(af0, c1, zero, 0, 0, 0);
#pragma unroll
        for (int r = 0; r < 16; ++r)
            run0[r] = fminf(run0[r], fminf(a00[r], a01[r]));
        f32x16 a10 = __builtin_amdgcn_mfma_f32_32x32x16_bf16(af1, c0, zero, 0, 0, 0);
        f32x16 a11 = __builtin_amdgcn_mfma_f32_32x32x16_bf16(af1, c1, zero, 0, 0, 0);
#pragma unroll
        for (int r = 0; r < 16; ++r)
            run1[r] = fminf(run1[r], fminf(a10[r], a11[r]));
    }

    // C/D layout (verified): col = lane&31, row = (r&3)+8*(r>>2)+4*(lane>>5)
    size_t obase = (((size_t)jh * 2 + dir) * BATCH + b) * NPTS + rowbase;
#pragma unroll
    for (int r = 0; r < 16; ++r) {
        float v0 = run0[r];
        float v1 = run1[r];
        v0 = fminf(v0, __shfl_xor(v0, 1, 32));
        v1 = fminf(v1, __shfl_xor(v1, 1, 32));
        v0 = fminf(v0, __shfl_xor(v0, 2, 32));
        v1 = fminf(v1, __shfl_xor(v1, 2, 32));
        v0 = fminf(v0, __shfl_xor(v0, 4, 32));
        v1 = fminf(v1, __shfl_xor(v1, 4, 32));
        v0 = fminf(v0, __shfl_xor(v0, 8, 32));
        v1 = fminf(v1, __shfl_xor(v1, 8, 32));
        v0 = fminf(v0, __shfl_xor(v0, 16, 32));
        v1 = fminf(v1, __shfl_xor(v1, 16, 32));
        if ((lane & 31) == 0) {
            int row = (r & 3) + 8 * (r >> 2) + 4 * (lane >> 5);
            part[obase + row]      = v0;
            part[obase + 32 + row] = v1;
        }
    }
}

// Stage 1: min over 8 jh splits, clamp, per-block sum (256 blocks).
__global__ __launch_bounds__(256) void reduce1_k(const float* __restrict__ part,
                                                 float* __restrict__ bsum) {
    int q = blockIdx.x * 256 + threadIdx.x;   // [0, 65536)
    float v = part[q];
#pragma unroll
    for (int jh = 1; jh < NJH; ++jh)
        v = fminf(v, part[(size_t)jh * 65536 + q]);
    v = fmaxf(v, 0.0f);
    for (int off = 32; off; off >>= 1) v += __shfl_down(v, off, 64);
    __shared__ float lds[4];
    int lane = threadIdx.x & 63, w = threadIdx.x >> 6;
    if (lane == 0) lds[w] = v;
    __syncthreads();
    if (threadIdx.x == 0)
        bsum[blockIdx.x] = (lds[0] + lds[1]) + (lds[2] + lds[3]);
}

// Stage 2: sum 256 block sums, scale.
__global__ __launch_bounds__(256) void reduce2_k(const float* __restrict__ bsum,
                                                 float* __restrict__ out) {
    float v = bsum[threadIdx.x];
    for (int off = 32; off; off >>= 1) v += __shfl_down(v, off, 64);
    __shared__ float lds[4];
    int lane = threadIdx.x & 63, w = threadIdx.x >> 6;
    if (lane == 0) lds[w] = v;
    __syncthreads();
    if (threadIdx.x == 0)
        out[0] = ((lds[0] + lds[1]) + (lds[2] + lds[3])) * (1.0f / 32768.0f);
}

extern "C" void kernel_launch(void* const* d_in, const int* in_sizes, int n_in,
                              void* d_out, int out_size, void* d_ws, size_t ws_size,
                              hipStream_t stream) {
    const float* pred = (const float*)d_in[0];
    const float* tgt  = (const float*)d_in[1];

    ushort* Apan = (ushort*)d_ws;                          // 2 MB
    ushort* Bpan = Apan + (size_t)2 * PTOT * 16;           // 2 MB
    float*  part = (float*)(Bpan + (size_t)2 * PTOT * 16); // NJH*2*PTOT floats = 2 MB
    float*  bsum = part + (size_t)NJH * 2 * PTOT;          // 256 floats

    pack_k<<<(2 * PTOT) / 256, 256, 0, stream>>>(pred, tgt, Apan, Bpan);
    chamfer_mfma_k<<<NJH * 2 * BATCH * 32, 256, 0, stream>>>(Apan, Bpan, part);
    reduce1_k<<<256, 256, 0, stream>>>(part, bsum);
    reduce2_k<<<1, 256, 0, stream>>>(bsum, (float*)d_out);
}